// Round 1
// baseline (68.235 us; speedup 1.0000x reference)
//
#include <hip/hip_runtime.h>
#include <math.h>

namespace {
constexpr int NV = 3;    // views
constexpr int NC = 16;   // channels
constexpr int ND = 32;   // depths
constexpr int NH = 256;
constexpr int NW = 320;
constexpr int HW = NH * NW;       // 81920
constexpr int DHW = ND * HW;      // 2621440
}

// ---------------------------------------------------------------------------
// Setup: build proj_v = P_v @ inv(P_0), store rot(9)+trans(3) per src view.
// P_v = [ K[:3,:3] @ E[:3,:4] ; E_row3 ]  (E_row3 == [0,0,0,1] here, but we
// keep the full 4x4 Gauss-Jordan inverse for robustness).
// mats layout: src view v (1..2) -> mats[(v-1)*12 + {0..8 rot row-major, 9..11 trans}]
// ---------------------------------------------------------------------------
__global__ void proj_setup_kernel(const float* __restrict__ pm,
                                  float* __restrict__ mats) {
    if (threadIdx.x != 0 || blockIdx.x != 0) return;
    float P[NV][4][4];
    for (int v = 0; v < NV; ++v) {
        const float* E = pm + v * 2 * 16;       // extrinsic 4x4
        const float* K = pm + v * 2 * 16 + 16;  // intrinsic 4x4
        for (int i = 0; i < 4; ++i)
            for (int j = 0; j < 4; ++j)
                P[v][i][j] = E[i * 4 + j];
        for (int i = 0; i < 3; ++i)
            for (int j = 0; j < 4; ++j) {
                float acc = 0.f;
                for (int k = 0; k < 3; ++k) acc += K[i * 4 + k] * E[k * 4 + j];
                P[v][i][j] = acc;
            }
    }
    // Gauss-Jordan inverse of P[0] with partial pivoting
    float A[4][8];
    for (int i = 0; i < 4; ++i)
        for (int j = 0; j < 4; ++j) {
            A[i][j] = P[0][i][j];
            A[i][j + 4] = (i == j) ? 1.f : 0.f;
        }
    for (int col = 0; col < 4; ++col) {
        int piv = col;
        float best = fabsf(A[col][col]);
        for (int r = col + 1; r < 4; ++r) {
            float av = fabsf(A[r][col]);
            if (av > best) { best = av; piv = r; }
        }
        if (piv != col)
            for (int j = 0; j < 8; ++j) {
                float t = A[col][j]; A[col][j] = A[piv][j]; A[piv][j] = t;
            }
        float inv = 1.f / A[col][col];
        for (int j = 0; j < 8; ++j) A[col][j] *= inv;
        for (int r = 0; r < 4; ++r) {
            if (r == col) continue;
            float f = A[r][col];
            if (f != 0.f)
                for (int j = 0; j < 8; ++j) A[r][j] -= f * A[col][j];
        }
    }
    float Inv[4][4];
    for (int i = 0; i < 4; ++i)
        for (int j = 0; j < 4; ++j) Inv[i][j] = A[i][j + 4];

    for (int v = 1; v < NV; ++v) {
        float M[4][4];
        for (int i = 0; i < 4; ++i)
            for (int j = 0; j < 4; ++j) {
                float acc = 0.f;
                for (int k = 0; k < 4; ++k) acc += P[v][i][k] * Inv[k][j];
                M[i][j] = acc;
            }
        float* o = mats + (v - 1) * 12;
        for (int i = 0; i < 3; ++i)
            for (int j = 0; j < 3; ++j) o[i * 3 + j] = M[i][j];
        for (int i = 0; i < 3; ++i) o[9 + i] = M[i][3];
    }
}

// ---------------------------------------------------------------------------
// Cost volume: one thread per (d, h, w). Writes cost into the prob region of
// d_out (reused as scratch; kernel2 reads then overwrites the same addresses).
// ---------------------------------------------------------------------------
__global__ __launch_bounds__(256) void cost_kernel(
    const float* __restrict__ feats,   // [V][C][HW]
    const float* __restrict__ dvals,   // [D][HW]
    const float* __restrict__ wreg,    // [C]
    const float* __restrict__ mats,    // [2][12]
    float* __restrict__ cost)          // [D][HW]
{
    __shared__ float s_mat[24];
    __shared__ float s_w[NC];
    int t = threadIdx.x;
    if (t < 24) s_mat[t] = mats[t];
    if (t < NC) s_w[t] = wreg[t];
    __syncthreads();

    int tid = blockIdx.x * blockDim.x + t;   // d*HW + n, exact grid
    int d = tid / HW;
    int n = tid - d * HW;
    int y = n / NW;
    int x = n - y * NW;
    float fx = (float)x, fy = (float)y;
    float depth = dvals[tid];

    float sum[NC], sq[NC];
#pragma unroll
    for (int c = 0; c < NC; ++c) {
        float r = feats[c * HW + n];   // ref view (v=0), coalesced
        sum[c] = r;
        sq[c] = r * r;
    }

#pragma unroll
    for (int v = 0; v < 2; ++v) {
        const float* m = s_mat + v * 12;
        float rx = m[0] * fx + m[1] * fy + m[2];
        float ry = m[3] * fx + m[4] * fy + m[5];
        float rz = m[6] * fx + m[7] * fy + m[8];
        float pxn = rx * depth + m[9];
        float pyn = ry * depth + m[10];
        float z   = rz * depth + m[11];
        z = (fabsf(z) < 1e-6f) ? 1e-6f : z;
        float px = pxn / z, py = pyn / z;
        float x0f = floorf(px), y0f = floorf(py);
        float wx = px - x0f, wy = py - y0f;
        int x0 = (int)x0f, y0 = (int)y0f;
        int x1 = x0 + 1, y1 = y0 + 1;
        bool vx0 = (x0 >= 0) && (x0 < NW), vx1 = (x1 >= 0) && (x1 < NW);
        bool vy0 = (y0 >= 0) && (y0 < NH), vy1 = (y1 >= 0) && (y1 < NH);
        int cx0 = min(max(x0, 0), NW - 1), cx1 = min(max(x1, 0), NW - 1);
        int cy0 = min(max(y0, 0), NH - 1), cy1 = min(max(y1, 0), NH - 1);
        int i00 = cy0 * NW + cx0, i01 = cy0 * NW + cx1;
        int i10 = cy1 * NW + cx0, i11 = cy1 * NW + cx1;
        float w00 = (1.f - wx) * (1.f - wy) * ((vx0 && vy0) ? 1.f : 0.f);
        float w01 = wx * (1.f - wy) * ((vx1 && vy0) ? 1.f : 0.f);
        float w10 = (1.f - wx) * wy * ((vx0 && vy1) ? 1.f : 0.f);
        float w11 = wx * wy * ((vx1 && vy1) ? 1.f : 0.f);
        const float* fv = feats + (v + 1) * NC * HW;
#pragma unroll
        for (int c = 0; c < NC; ++c) {
            const float* fc = fv + c * HW;
            float val = fc[i00] * w00 + fc[i01] * w01 + fc[i10] * w10 + fc[i11] * w11;
            sum[c] += val;
            sq[c] += val * val;
        }
    }

    float cst = 0.f;
    const float invV = 1.f / 3.f;
#pragma unroll
    for (int c = 0; c < NC; ++c) {
        float s = sum[c] * invV;
        float var = sq[c] * invV - s * s;
        cst += var * s_w[c];
    }
    cost[tid] = cst;
}

// ---------------------------------------------------------------------------
// Softmax over D per pixel + depth regression + confidence. Reads cost from
// the prob region, overwrites it with prob. All register arrays are indexed
// only by compile-time constants (unrolled) to avoid scratch.
// ---------------------------------------------------------------------------
__global__ __launch_bounds__(256) void softmax_kernel(
    const float* __restrict__ dvals,  // [D][HW]
    float* __restrict__ out)          // depth[HW] | conf[HW] | prob[D*HW]
{
    int n = blockIdx.x * blockDim.x + threadIdx.x;  // pixel, exact grid
    float* prob = out + 2 * HW;

    float c[ND];
    float mx = -INFINITY;
#pragma unroll
    for (int d = 0; d < ND; ++d) {
        c[d] = prob[d * HW + n];
        mx = fmaxf(mx, c[d]);
    }
    float ssum = 0.f;
#pragma unroll
    for (int d = 0; d < ND; ++d) {
        float e = expf(c[d] - mx);
        c[d] = e;
        ssum += e;
    }
    float inv = 1.f / ssum;
    float depth_acc = 0.f, didx_acc = 0.f;
#pragma unroll
    for (int d = 0; d < ND; ++d) {
        float pv = c[d] * inv;
        c[d] = pv;
        prob[d * HW + n] = pv;
        depth_acc += pv * dvals[d * HW + n];
        didx_acc += pv * (float)d;
    }
    int di = (int)didx_acc;            // trunc toward zero, matches astype(int32)
    di = min(max(di, 0), ND - 1);
    float pdi = 0.f, pdi1 = 0.f;
#pragma unroll
    for (int d = 0; d < ND; ++d) {
        pdi = (d == di) ? c[d] : pdi;
        pdi1 = (d == di + 1) ? c[d] : pdi1;
    }
    out[n] = depth_acc;
    out[HW + n] = pdi + pdi1;
}

extern "C" void kernel_launch(void* const* d_in, const int* in_sizes, int n_in,
                              void* d_out, int out_size, void* d_ws, size_t ws_size,
                              hipStream_t stream) {
    const float* feats = (const float*)d_in[0];   // (V,B,C,H,W)
    const float* pm    = (const float*)d_in[1];   // (B,V,2,4,4)
    const float* dvals = (const float*)d_in[2];   // (B,D,H,W)
    const float* wreg  = (const float*)d_in[3];   // (C,)
    float* out = (float*)d_out;
    float* mats = (float*)d_ws;                   // 24 floats

    proj_setup_kernel<<<1, 64, 0, stream>>>(pm, mats);
    cost_kernel<<<DHW / 256, 256, 0, stream>>>(feats, dvals, wreg, mats,
                                               out + 2 * HW);
    softmax_kernel<<<HW / 256, 256, 0, stream>>>(dvals, out);
}